// Round 12
// baseline (3243.703 us; speedup 1.0000x reference)
//
#include <hip/hip_runtime.h>
#include <cstdint>
#include <cstddef>

#define V_SZ 32000
#define H_SZ 1024
#define T_SZ 512
#define B_SZ 64

typedef short short8 __attribute__((ext_vector_type(8)));
typedef float f32x4 __attribute__((ext_vector_type(4)));
typedef unsigned long long u64;

__device__ __forceinline__ short f2bf(float f) {
  union { float f; unsigned u; } v; v.f = f;
  unsigned r = (v.u + 0x7fffu + ((v.u >> 16) & 1u)) >> 16;  // RNE, inputs finite
  return (short)r;
}

__device__ __forceinline__ unsigned cvtpk(float a, float b) {  // lo=bf16(a), hi=bf16(b)
  unsigned r;
  asm("v_cvt_pk_bf16_f32 %0, %1, %2" : "=v"(r) : "v"(a), "v"(b));
  return r;
}

__device__ __forceinline__ void cs8(u64* p, u64 v) {
  __hip_atomic_store(p, v, __ATOMIC_RELAXED, __HIP_MEMORY_SCOPE_AGENT);
}

__device__ __forceinline__ float fsig(float x) {   // 1/(1+e^-x) via v_exp/v_rcp
  return __builtin_amdgcn_rcpf(1.f + __builtin_amdgcn_exp2f(x * -1.44269504f));
}
__device__ __forceinline__ float ftanh(float x) {  // 1 - 2/(e^2x+1)
  return 1.f - 2.f * __builtin_amdgcn_rcpf(1.f + __builtin_amdgcn_exp2f(x * 2.88539008f));
}

// embT[v][h] = bf16(emb_w[h][v] + emb_b[h])  -- tiled transpose, both sides coalesced
__global__ __launch_bounds__(256) void k_embT(const float* __restrict__ emb_w,
                                              const float* __restrict__ emb_b,
                                              short* __restrict__ embT) {
  __shared__ float tile[64][65];
  const int v0 = blockIdx.x * 64, h0 = blockIdx.y * 64;
  const int c = threadIdx.x & 63, rg = threadIdx.x >> 6;
#pragma unroll
  for (int p = 0; p < 16; ++p) {
    int r = rg * 16 + p;
    tile[r][c] = emb_w[(size_t)(h0 + r) * V_SZ + v0 + c];
  }
  __syncthreads();
  const float bias = emb_b[h0 + c];
#pragma unroll
  for (int p = 0; p < 16; ++p) {
    int vr = rg * 16 + p;
    embT[(size_t)(v0 + vr) * H_SZ + h0 + c] = f2bf(tile[c][vr] + bias);
  }
}

__global__ __launch_bounds__(256) void k_cast(const float* __restrict__ s,
                                              short* __restrict__ d, int n) {
  for (int i = blockIdx.x * 256 + threadIdx.x; i < n; i += gridDim.x * 256)
    d[i] = f2bf(s[i]);
}

__global__ __launch_bounds__(256) void k_copy(const float* __restrict__ s,
                                              float* __restrict__ d, int n) {
  for (int i = blockIdx.x * 256 + threadIdx.x; i < n; i += gridDim.x * 256)
    d[i] = s[i];
}

// Persistent bidirectional LSTM. 256 blocks x 512 threads, 1 block/CU.
// block: d = bid>>7, bg = (bid&127)>>6, cg = bid&63, n0 = cg*16.
// wave w owns K-chunks {w*32 + jj*256} (4 x + 4 h).
// PER-WAVE publish: each wave packs its own 64 h values in-register
// (cvt_pk + shfl), 16x8B UC stores, vmcnt(0), sets flag[cg][w]=t+1.
// PER-WAVE poll: wave w needs only 8 producer blocks {q*16+2w+i}; its 64
// lanes poll those blocks' 8x8 wave-flags (lane = (q,i,wp)), __all-ballot.
// 2-phase hbf safe: publish(t+2) is after S1(t+1), which needs all 8 waves'
// polls(t+1) whose producer-set union = all 64 blocks x 8 waves >= t+1
// => every reader of h(t) finished. Weights in regs; c-state in reg.
__global__ __launch_bounds__(512, 2) void k_persist(
    const int* __restrict__ tokens, const short* __restrict__ embT,
    const short* __restrict__ Wbf, const float* __restrict__ biasws,
    short* __restrict__ hbf, unsigned* __restrict__ bar,
    float* __restrict__ out) {
  __shared__ float P_lds[8][32][68];   // [K-eighth][b32][64 cols + 4 pad]

  const int tid = threadIdx.x;
  const int lane = tid & 63, w = tid >> 6;
  const int l15 = lane & 15, l4 = lane >> 4;
  const int d = (int)(blockIdx.x >> 7);
  const int bflat = (int)(blockIdx.x & 127);
  const int bg = bflat >> 6;                 // batch half
  const int cg = bflat & 63;                 // col group
  const int n0 = cg << 4;
  const int r0 = bg * 32 + l15, r1 = r0 + 16;  // A-fragment batch rows
  const int kw = w * 32 + l4 * 8;              // lane k-base

  // ---- step-invariant B fragments in registers: chunk w+jj*8, N-tile nt ----
  short8 Bf[8][4];
#pragma unroll
  for (int jj = 0; jj < 8; ++jj) {
    int slab = w + jj * 8;
#pragma unroll
    for (int nt = 0; nt < 4; ++nt) {
      int row64 = nt * 16 + l15;             // flat (gate,col) 0..63
      size_t grow = (size_t)((d * 4 + (row64 >> 4)) * 1024 + n0 + (row64 & 15));
      Bf[jj][nt] = *(const short8*)(Wbf + grow * 2048 + slab * 32 + l4 * 8);
    }
  }

  // ---- gate-phase constants: thread owns (b32=tid>>4, c16=tid&15) ----
  const int b32 = tid >> 4, c16 = tid & 15;
  const int gcol = n0 + c16, gbrow = bg * 32 + b32;
  float brg[4];
#pragma unroll
  for (int g4 = 0; g4 < 4; ++g4) brg[g4] = biasws[d * 4096 + g4 * 1024 + gcol];
  float c_reg = 0.f;

  // ---- dataflow flags: u32 [d][bg][cg][wave]; monotone, no reset ----
  unsigned* const grpf = bar + (d * 2 + bg) * 512;
  unsigned* const fpub = grpf + cg * 8 + w;          // this wave's own flag
  unsigned* const fpoll =                            // lane -> (q,i,wp) flag
      grpf + ((lane >> 4) * 16 + 2 * w + ((lane >> 3) & 1)) * 8 + (lane & 7);

  const f32x4 fzero = {0.f, 0.f, 0.f, 0.f};
  f32x4 acc[2][4];

  // x-half of step s (token-dependent only): cached direct-to-frag + 32 MFMA.
  auto X_PHASE = [&](int s) {
    const int td = d ? (T_SZ - 1 - s) : s;
    const short* xb0 = embT + (size_t)tokens[td * B_SZ + r0] * 1024 + kw;
    const short* xb1 = embT + (size_t)tokens[td * B_SZ + r1] * 1024 + kw;
    short8 xf[2][4];
#pragma unroll
    for (int jj = 0; jj < 4; ++jj) {         // chunk w+jj*8 -> +jj*256 elements
      xf[0][jj] = *(const short8*)(xb0 + jj * 256);
      xf[1][jj] = *(const short8*)(xb1 + jj * 256);
    }
#pragma unroll
    for (int ms = 0; ms < 2; ++ms)
#pragma unroll
      for (int nt = 0; nt < 4; ++nt) acc[ms][nt] = fzero;
#pragma unroll
    for (int jj = 0; jj < 4; ++jj)
#pragma unroll
      for (int ms = 0; ms < 2; ++ms)
#pragma unroll
        for (int nt = 0; nt < 4; ++nt)
          acc[ms][nt] = __builtin_amdgcn_mfma_f32_16x16x32_bf16(
              xf[ms][jj], Bf[jj][nt], acc[ms][nt], 0, 0, 0);
  };

  X_PHASE(0);  // prologue

  for (int t = 0; t < T_SZ; ++t) {
    if (t > 0) {
      // ---- per-wave poll: my 8 producers' 8 wave-flags >= t ----
      const unsigned tgt = (unsigned)t;
      while (true) {
        unsigned v = __hip_atomic_load(fpoll, __ATOMIC_RELAXED,
                                       __HIP_MEMORY_SCOPE_AGENT);
        if (__all(v >= tgt)) break;
        __builtin_amdgcn_s_sleep(1);
      }
      // ---- h-half: UC 16B fragment loads (early-clobber blob) + 32 MFMA ----
      const short* hsrc = hbf + ((t & 1) * 2 + d) * 65536;
      const short* hb0 = hsrc + r0 * 1024 + kw;
      const short* hb1 = hsrc + r1 * 1024 + kw;
      short8 hf[2][4];
      asm volatile(
          "global_load_dwordx4 %0, %8, off sc0 sc1\n\t"
          "global_load_dwordx4 %1, %8, off offset:512 sc0 sc1\n\t"
          "global_load_dwordx4 %2, %8, off offset:1024 sc0 sc1\n\t"
          "global_load_dwordx4 %3, %8, off offset:1536 sc0 sc1\n\t"
          "global_load_dwordx4 %4, %9, off sc0 sc1\n\t"
          "global_load_dwordx4 %5, %9, off offset:512 sc0 sc1\n\t"
          "global_load_dwordx4 %6, %9, off offset:1024 sc0 sc1\n\t"
          "global_load_dwordx4 %7, %9, off offset:1536 sc0 sc1\n\t"
          "s_waitcnt vmcnt(0)"
          : "=&v"(hf[0][0]), "=&v"(hf[0][1]), "=&v"(hf[0][2]), "=&v"(hf[0][3]),
            "=&v"(hf[1][0]), "=&v"(hf[1][1]), "=&v"(hf[1][2]), "=&v"(hf[1][3])
          : "v"(hb0), "v"(hb1)
          : "memory");
#pragma unroll
      for (int q = 0; q < 4; ++q)
#pragma unroll
        for (int ms = 0; ms < 2; ++ms)
#pragma unroll
          for (int nt = 0; nt < 4; ++nt)
            acc[ms][nt] = __builtin_amdgcn_mfma_f32_16x16x32_bf16(
                hf[ms][q], Bf[4 + q][nt], acc[ms][nt], 0, 0, 0);
    }

    // ---- K-split partial dump (C layout: row=l4*4+i, col=l15) ----
#pragma unroll
    for (int ms = 0; ms < 2; ++ms)
#pragma unroll
      for (int nt = 0; nt < 4; ++nt)
#pragma unroll
        for (int i = 0; i < 4; ++i)
          P_lds[w][ms * 16 + l4 * 4 + i][nt * 16 + l15] = acc[ms][nt][i];
    __syncthreads();  // S1

    // ---- gate math + state update (thread: b32, c16) ----
    float pr[4];
#pragma unroll
    for (int g4 = 0; g4 < 4; ++g4) {
      float s = brg[g4];
#pragma unroll
      for (int q = 0; q < 8; ++q) s += P_lds[q][b32][g4 * 16 + c16];
      pr[g4] = s;
    }
    float ig = fsig(pr[0]);
    float og = fsig(pr[1]);
    float fg = fsig(pr[2]);
    float cg4 = ftanh(pr[3]);
    c_reg = fg * c_reg + ig * cg4;
    float hnew = og * ftanh(c_reg);

    if (t < T_SZ - 1) {
      // ---- per-wave publish: in-register pack -> 16x8B UC -> drain -> flag ----
      short* hdst = hbf + (((t + 1) & 1) * 2 + d) * 65536;
      float nb = __shfl_down(hnew, 1);
      unsigned ulo = cvtpk(hnew, nb);            // cols c, c+1
      unsigned uhi = __shfl_down(ulo, 2);        // cols c+2, c+3
      if ((lane & 3) == 0) {
        u64 pk = ((u64)uhi << 32) | (u64)ulo;
        // this thread's row = b32 = w*4 + (lane>>4); cols (lane&15)..+3
        cs8((u64*)(hdst + (size_t)gbrow * 1024 + n0 + (lane & 15)), pk);
      }
      asm volatile("s_waitcnt vmcnt(0)" ::: "memory");
      if (lane == 0)
        __hip_atomic_store(fpub, (unsigned)(t + 1), __ATOMIC_RELAXED,
                           __HIP_MEMORY_SCOPE_AGENT);
    }

    // out[] stores (plain cached, off critical path)
    size_t o = (size_t)(t * B_SZ + gbrow) * 2048 + (size_t)d * 1024 + gcol;
    out[o] = hnew;
    out[o + 67108864] = c_reg;

    __syncthreads();  // S2: all gate reads done -> next dump safe; skew proof holds
    if (t < T_SZ - 1) X_PHASE(t + 1);  // overlap flag propagation + h-latency
  }
}

extern "C" void kernel_launch(void* const* d_in, const int* in_sizes, int n_in,
                              void* d_out, int out_size, void* d_ws, size_t ws_size,
                              hipStream_t stream) {
  (void)in_sizes; (void)n_in; (void)out_size; (void)ws_size;
  const int* tokens  = (const int*)d_in[0];
  const float* emb_w = (const float*)d_in[1];
  const float* emb_b = (const float*)d_in[2];

  char* ws = (char*)d_ws;
  short* embT   = (short*)(ws);               // 65,536,000 B
  short* Wbf    = (short*)(ws + 65536000);    // 33,554,432 B
  float* biasws = (float*)(ws + 99090432);    //     32,768 B
  short* hbf    = (short*)(ws + 99123200);    //    524,288 B (2 phase x 2 dir x 64x1024)
  unsigned* bar = (unsigned*)(ws + 99647488); //      8,192 B (per-wave flags)

  (void)hipMemsetAsync(ws + 99647488, 0, 8192, stream);

  k_embT<<<dim3(500, 16), 256, 0, stream>>>(emb_w, emb_b, embT);

  for (int d = 0; d < 2; ++d)
    for (int g = 0; g < 4; ++g) {
      const float* wsrc = (const float*)d_in[3 + d * 8 + g * 2];
      const float* bsrc = (const float*)d_in[4 + d * 8 + g * 2];
      k_cast<<<1024, 256, 0, stream>>>(wsrc, Wbf + (size_t)(d * 4 + g) * 1024 * 2048,
                                       1024 * 2048);
      k_copy<<<4, 256, 0, stream>>>(bsrc, biasws + (d * 4 + g) * 1024, 1024);
    }

  float* outp = (float*)d_out;
  void* kargs[] = {(void*)&tokens, (void*)&embT, (void*)&Wbf, (void*)&biasws,
                   (void*)&hbf, (void*)&bar, (void*)&outp};
  (void)hipLaunchCooperativeKernel((const void*)k_persist, dim3(256), dim3(512), kargs,
                                   0, stream);
}